// Round 1
// baseline (1072.683 us; speedup 1.0000x reference)
//
#include <hip/hip_runtime.h>

// WaveNet on gfx950, fp16 MFMA path.
// Key tricks: global-time-coordinate res buffers (no shifting), skip telescoping
// (final = R20 - R0, skip buffer eliminated), f/g rows interleaved per wave so the
// gate is computed in registers, fp32 res master for accuracy, fp16 matmul inputs.

#define TT 8192
#define HIDC 128
#define GOODC 2046
#define TGT 6146
#define NL 20

typedef _Float16 half8_t __attribute__((ext_vector_type(8)));
typedef _Float16 half4_t __attribute__((ext_vector_type(4)));
typedef float floatx4 __attribute__((ext_vector_type(4)));

__device__ __forceinline__ floatx4 mfma16(half8_t a, half8_t b, floatx4 c) {
  return __builtin_amdgcn_mfma_f32_16x16x32_f16(a, b, c, 0, 0, 0);
}

// ---------------- weight prep: fp32 -> fp16, stacked layouts ----------------
__global__ void prep_kernel(const float* __restrict__ Wi, const float* __restrict__ Wf,
                            const float* __restrict__ Wg, const float* __restrict__ Wr,
                            const float* __restrict__ W1, const float* __restrict__ W2,
                            _Float16* __restrict__ WIh, _Float16* __restrict__ WFG,
                            _Float16* __restrict__ WRh, _Float16* __restrict__ W1h,
                            _Float16* __restrict__ W2h) {
  int idx = blockIdx.x * blockDim.x + threadIdx.x;
  int stride = gridDim.x * blockDim.x;
  // WFG[l][m][k]: m<128 -> Wf row m, else Wg row m-128; k<128 -> tap0 (u-d), else tap1 (u)
  for (int i = idx; i < NL * 256 * 256; i += stride) {
    int l = i >> 16; int m = (i >> 8) & 255; int k = i & 255;
    int tap = k >> 7; int ci = k & 127;
    float v;
    if (m < 128) v = Wf[(((size_t)l * 128 + m) * 128 + ci) * 2 + tap];
    else         v = Wg[(((size_t)l * 128 + (m - 128)) * 128 + ci) * 2 + tap];
    WFG[i] = (_Float16)v;
  }
  for (int i = idx; i < NL * 128 * 128; i += stride) WRh[i] = (_Float16)Wr[i];
  for (int i = idx; i < 128 * 256; i += stride) WIh[i] = (_Float16)Wi[i];
  for (int i = idx; i < 512 * 128; i += stride) W1h[i] = (_Float16)W1[i];
  for (int i = idx; i < 256 * 512; i += stride) W2h[i] = (_Float16)W2[i];
}

// ---------------- input 1x1 conv: R0[b][u][c] = Wi @ inputs + bi ----------------
__global__ __launch_bounds__(256, 3) void input_kernel(
    const float* __restrict__ inp, const _Float16* __restrict__ WIh,
    const float* __restrict__ bi, float* __restrict__ R0) {
  __shared__ __align__(16) _Float16 Xs[64][264];  // [n][k=256], pad 8
  const int tid = threadIdx.x;
  const int lane = tid & 63;
  const int w = tid >> 6;
  const int ml = lane & 15;
  const int mq = lane >> 4;
  const int b = blockIdx.y;
  const int u0 = blockIdx.x * 64;
  const float* ib = inp + (size_t)b * 256 * TT;

  // stage + transpose: inputs[b][k][t] (t-contig) -> Xs[n][k] (k-contig), fp16
  for (int i = tid; i < 64 * 16; i += 256) {
    int n4 = i & 15;   // t-group of 4
    int kg = i >> 4;   // channel-group of 4
    const float* src = ib + (size_t)(kg * 4) * TT + u0 + n4 * 4;
    floatx4 c0 = *(const floatx4*)(src);
    floatx4 c1 = *(const floatx4*)(src + TT);
    floatx4 c2 = *(const floatx4*)(src + 2 * TT);
    floatx4 c3 = *(const floatx4*)(src + 3 * TT);
#pragma unroll
    for (int t = 0; t < 4; ++t) {
      half4_t h;
      h[0] = (_Float16)c0[t]; h[1] = (_Float16)c1[t];
      h[2] = (_Float16)c2[t]; h[3] = (_Float16)c3[t];
      *(half4_t*)&Xs[n4 * 4 + t][kg * 4] = h;
    }
  }
  __syncthreads();

  floatx4 acc[2][4];
#pragma unroll
  for (int a = 0; a < 2; ++a)
#pragma unroll
    for (int c = 0; c < 4; ++c) acc[a][c] = floatx4{0.f, 0.f, 0.f, 0.f};

  const _Float16* Aw = WIh + (size_t)(32 * w + ml) * 256;
  for (int kk = 0; kk < 8; ++kk) {
    const int ko = kk * 32 + mq * 8;
    half8_t a0 = *(const half8_t*)(Aw + ko);
    half8_t a1 = *(const half8_t*)(Aw + 16 * 256 + ko);
#pragma unroll
    for (int nt = 0; nt < 4; ++nt) {
      half8_t bv = *(const half8_t*)&Xs[nt * 16 + ml][ko];
      acc[0][nt] = mfma16(a0, bv, acc[0][nt]);
      acc[1][nt] = mfma16(a1, bv, acc[1][nt]);
    }
  }
  __syncthreads();
  float* Xf = (float*)&Xs[0][0];  // reuse as [64][132] fp32 (same 33792 B)
#pragma unroll
  for (int mt = 0; mt < 2; ++mt) {
    const int mb = 32 * w + mt * 16 + mq * 4;
#pragma unroll
    for (int nt = 0; nt < 4; ++nt)
      *(floatx4*)&Xf[(nt * 16 + ml) * 132 + mb] = acc[mt][nt];
  }
  __syncthreads();
  float* Rb = R0 + (size_t)b * TT * HIDC;
  for (int i = tid; i < 64 * 32; i += 256) {
    int grp = i & 31; int n = i >> 5;
    floatx4 xv = *(const floatx4*)&Xf[n * 132 + grp * 4];
    floatx4 bv = *(const floatx4*)(bi + grp * 4);
    *(floatx4*)(Rb + (size_t)(u0 + n) * HIDC + grp * 4) = xv + bv;
  }
}

// ---------------- one residual layer ----------------
__global__ __launch_bounds__(256, 3) void layer_kernel(
    const float* __restrict__ Rin, float* __restrict__ Rout,
    const _Float16* __restrict__ WFG, const _Float16* __restrict__ WR,
    const float* __restrict__ bf, const float* __restrict__ bg,
    const float* __restrict__ br, int d, int ustart) {
  __shared__ __align__(16) _Float16 Xs[64][264];  // taps [n][k=256] (k<128: u-d, else u)
  __shared__ __align__(16) _Float16 Os[64][136];  // gated out [n][m=128]
  const int tid = threadIdx.x;
  const int lane = tid & 63;
  const int w = tid >> 6;
  const int ml = lane & 15;
  const int mq = lane >> 4;
  const int b = blockIdx.y;
  const int u0 = ustart + blockIdx.x * 64;
  const float* Rb = Rin + (size_t)b * TT * HIDC;
  float* Ro = Rout + (size_t)b * TT * HIDC;

  // stage both taps fp32->fp16
  for (int i = tid; i < 64 * 64; i += 256) {
    int grp = i & 31;
    int tap = (i >> 5) & 1;
    int n = i >> 6;
    int u = u0 + n - (tap ? 0 : d);
    if (u > TT - 1) u = TT - 1;  // tail clamp (values unused)
    floatx4 v = *(const floatx4*)(Rb + (size_t)u * HIDC + grp * 4);
    half4_t h;
    h[0] = (_Float16)v[0]; h[1] = (_Float16)v[1];
    h[2] = (_Float16)v[2]; h[3] = (_Float16)v[3];
    *(half4_t*)&Xs[n][tap * 128 + grp * 4] = h;
  }
  __syncthreads();

  // GEMM1: [f;g] = WFG(256x256) @ taps. wave w owns f-rows AND g-rows [32w,32w+32)
  floatx4 accF[2][4], accG[2][4];
#pragma unroll
  for (int a = 0; a < 2; ++a)
#pragma unroll
    for (int c = 0; c < 4; ++c) {
      accF[a][c] = floatx4{0.f, 0.f, 0.f, 0.f};
      accG[a][c] = floatx4{0.f, 0.f, 0.f, 0.f};
    }
  const _Float16* Af = WFG + (size_t)(32 * w + ml) * 256;
  const _Float16* Ag = WFG + (size_t)(128 + 32 * w + ml) * 256;
  for (int kk = 0; kk < 8; ++kk) {
    const int ko = kk * 32 + mq * 8;
    half8_t aF0 = *(const half8_t*)(Af + ko);
    half8_t aF1 = *(const half8_t*)(Af + 16 * 256 + ko);
    half8_t aG0 = *(const half8_t*)(Ag + ko);
    half8_t aG1 = *(const half8_t*)(Ag + 16 * 256 + ko);
#pragma unroll
    for (int nt = 0; nt < 4; ++nt) {
      half8_t bv = *(const half8_t*)&Xs[nt * 16 + ml][ko];
      accF[0][nt] = mfma16(aF0, bv, accF[0][nt]);
      accF[1][nt] = mfma16(aF1, bv, accF[1][nt]);
      accG[0][nt] = mfma16(aG0, bv, accG[0][nt]);
      accG[1][nt] = mfma16(aG1, bv, accG[1][nt]);
    }
  }

  // gate in registers: out = tanh(f+bf) * sigmoid(g+bg) -> Os[n][m]
#pragma unroll
  for (int mt = 0; mt < 2; ++mt) {
    const int mb = 32 * w + mt * 16 + mq * 4;
    floatx4 bfv = *(const floatx4*)(bf + mb);
    floatx4 bgv = *(const floatx4*)(bg + mb);
#pragma unroll
    for (int nt = 0; nt < 4; ++nt) {
      half4_t o;
#pragma unroll
      for (int r = 0; r < 4; ++r) {
        float fp = accF[mt][nt][r] + bfv[r];
        float gp = accG[mt][nt][r] + bgv[r];
        float fv = 2.0f / (1.0f + __expf(-2.0f * fp)) - 1.0f;  // tanh
        float gv = 1.0f / (1.0f + __expf(-gp));                // sigmoid
        o[r] = (_Float16)(fv * gv);
      }
      *(half4_t*)&Os[nt * 16 + ml][mb] = o;
    }
  }
  __syncthreads();

  // GEMM2: x = WR(128x128) @ out
  floatx4 accX[2][4];
#pragma unroll
  for (int a = 0; a < 2; ++a)
#pragma unroll
    for (int c = 0; c < 4; ++c) accX[a][c] = floatx4{0.f, 0.f, 0.f, 0.f};
  const _Float16* Ar = WR + (size_t)(32 * w + ml) * 128;
#pragma unroll
  for (int kk = 0; kk < 4; ++kk) {
    const int ko = kk * 32 + mq * 8;
    half8_t a0 = *(const half8_t*)(Ar + ko);
    half8_t a1 = *(const half8_t*)(Ar + 16 * 128 + ko);
#pragma unroll
    for (int nt = 0; nt < 4; ++nt) {
      half8_t bv = *(const half8_t*)&Os[nt * 16 + ml][ko];
      accX[0][nt] = mfma16(a0, bv, accX[0][nt]);
      accX[1][nt] = mfma16(a1, bv, accX[1][nt]);
    }
  }
  __syncthreads();  // all Os reads + (earlier) Xs reads complete

  // transpose x through LDS (reuse Xs as fp32 [64][132]) for coalesced epilogue
  float* Xf = (float*)&Xs[0][0];
#pragma unroll
  for (int mt = 0; mt < 2; ++mt) {
    const int mb = 32 * w + mt * 16 + mq * 4;
#pragma unroll
    for (int nt = 0; nt < 4; ++nt)
      *(floatx4*)&Xf[(nt * 16 + ml) * 132 + mb] = accX[mt][nt];
  }
  __syncthreads();

  // epilogue: R_new[u] = x + br + R_old[u]   (skip accumulation telescopes away)
  for (int i = tid; i < 64 * 32; i += 256) {
    int grp = i & 31; int n = i >> 5;
    int u = u0 + n;
    if (u < TT) {
      floatx4 xv = *(const floatx4*)&Xf[n * 132 + grp * 4];
      floatx4 rv = *(const floatx4*)(Rb + (size_t)u * HIDC + grp * 4);
      floatx4 bv = *(const floatx4*)(br + grp * 4);
      *(floatx4*)(Ro + (size_t)u * HIDC + grp * 4) = xv + rv + bv;
    }
  }
}

// ---------------- head: out = W2 @ relu(W1 @ relu(R20-R0) + b1) + b2 ----------------
__global__ __launch_bounds__(256, 3) void head_kernel(
    const float* __restrict__ Rfin, const float* __restrict__ R0,
    const _Float16* __restrict__ W1h, const _Float16* __restrict__ W2h,
    const float* __restrict__ b1, const float* __restrict__ b2,
    float* __restrict__ out) {
  __shared__ __align__(16) _Float16 Hs[32][136];   // relu(final) [n][c=128]
  __shared__ __align__(16) _Float16 H1s[32][520];  // mid [n][m=512]
  const int tid = threadIdx.x;
  const int lane = tid & 63;
  const int w = tid >> 6;
  const int ml = lane & 15;
  const int mq = lane >> 4;
  const int b = blockIdx.y;
  const int u0 = GOODC + blockIdx.x * 32;
  const float* Ra = Rfin + (size_t)b * TT * HIDC;
  const float* Rz = R0 + (size_t)b * TT * HIDC;

  for (int i = tid; i < 32 * 32; i += 256) {
    int grp = i & 31; int n = i >> 5;
    int u = u0 + n; if (u > TT - 1) u = TT - 1;
    floatx4 a = *(const floatx4*)(Ra + (size_t)u * HIDC + grp * 4);
    floatx4 z = *(const floatx4*)(Rz + (size_t)u * HIDC + grp * 4);
    half4_t h;
#pragma unroll
    for (int t = 0; t < 4; ++t) {
      float v = a[t] - z[t];
      h[t] = (_Float16)(v > 0.f ? v : 0.f);
    }
    *(half4_t*)&Hs[n][grp * 4] = h;
  }
  __syncthreads();

  // GEMM1: M=512 K=128; wave w rows [128w, 128w+128)
  floatx4 acc1[8][2];
#pragma unroll
  for (int a = 0; a < 8; ++a) { acc1[a][0] = floatx4{0.f,0.f,0.f,0.f}; acc1[a][1] = floatx4{0.f,0.f,0.f,0.f}; }
  const _Float16* A1 = W1h + (size_t)(128 * w + ml) * 128;
#pragma unroll
  for (int kk = 0; kk < 4; ++kk) {
    const int ko = kk * 32 + mq * 8;
    half8_t bv0 = *(const half8_t*)&Hs[ml][ko];
    half8_t bv1 = *(const half8_t*)&Hs[16 + ml][ko];
#pragma unroll
    for (int mt = 0; mt < 8; ++mt) {
      half8_t av = *(const half8_t*)(A1 + (size_t)(mt * 16) * 128 + ko);
      acc1[mt][0] = mfma16(av, bv0, acc1[mt][0]);
      acc1[mt][1] = mfma16(av, bv1, acc1[mt][1]);
    }
  }
#pragma unroll
  for (int mt = 0; mt < 8; ++mt) {
    const int mb = 128 * w + mt * 16 + mq * 4;
    floatx4 bv = *(const floatx4*)(b1 + mb);
#pragma unroll
    for (int nt = 0; nt < 2; ++nt) {
      half4_t h;
#pragma unroll
      for (int r = 0; r < 4; ++r) {
        float v = acc1[mt][nt][r] + bv[r];
        h[r] = (_Float16)(v > 0.f ? v : 0.f);
      }
      *(half4_t*)&H1s[nt * 16 + ml][mb] = h;
    }
  }
  __syncthreads();

  // GEMM2: M=256 K=512; wave w rows [64w, 64w+64)
  floatx4 acc2[4][2];
#pragma unroll
  for (int a = 0; a < 4; ++a) { acc2[a][0] = floatx4{0.f,0.f,0.f,0.f}; acc2[a][1] = floatx4{0.f,0.f,0.f,0.f}; }
  const _Float16* A2 = W2h + (size_t)(64 * w + ml) * 512;
  for (int kk = 0; kk < 16; ++kk) {
    const int ko = kk * 32 + mq * 8;
    half8_t bv0 = *(const half8_t*)&H1s[ml][ko];
    half8_t bv1 = *(const half8_t*)&H1s[16 + ml][ko];
#pragma unroll
    for (int mt = 0; mt < 4; ++mt) {
      half8_t av = *(const half8_t*)(A2 + (size_t)(mt * 16) * 512 + ko);
      acc2[mt][0] = mfma16(av, bv0, acc2[mt][0]);
      acc2[mt][1] = mfma16(av, bv1, acc2[mt][1]);
    }
  }
  __syncthreads();  // H1s reads done; reuse as fp32 [32][260]
  float* Of = (float*)&H1s[0][0];
#pragma unroll
  for (int mt = 0; mt < 4; ++mt) {
    const int mb = 64 * w + mt * 16 + mq * 4;
    floatx4 bv = *(const floatx4*)(b2 + mb);
#pragma unroll
    for (int nt = 0; nt < 2; ++nt)
      *(floatx4*)&Of[(nt * 16 + ml) * 260 + mb] = acc2[mt][nt] + bv;
  }
  __syncthreads();
  for (int i = tid; i < 32 * 64; i += 256) {
    int grp = i & 63; int n = i >> 6;
    int u = u0 + n;
    if (u < TT) {
      floatx4 v = *(const floatx4*)&Of[n * 260 + grp * 4];
      *(floatx4*)(out + ((size_t)b * TGT + (u - GOODC)) * 256 + grp * 4) = v;
    }
  }
}

extern "C" void kernel_launch(void* const* d_in, const int* in_sizes, int n_in,
                              void* d_out, int out_size, void* d_ws, size_t ws_size,
                              hipStream_t stream) {
  const float* inputs = (const float*)d_in[0];
  const float* Wi = (const float*)d_in[1];
  const float* bi = (const float*)d_in[2];
  const float* Wf = (const float*)d_in[3];
  const float* bf = (const float*)d_in[4];
  const float* Wg = (const float*)d_in[5];
  const float* bg = (const float*)d_in[6];
  const float* Wr = (const float*)d_in[7];
  const float* br = (const float*)d_in[8];
  const float* W1 = (const float*)d_in[9];
  const float* b1 = (const float*)d_in[10];
  const float* W2 = (const float*)d_in[11];
  const float* b2 = (const float*)d_in[12];
  float* out = (float*)d_out;

  // workspace layout (~104.4 MB): three fp32 res buffers + fp16 weights
  char* ws = (char*)d_ws;
  float* R0 = (float*)(ws + 0);
  float* P  = (float*)(ws + 33554432);
  float* Q  = (float*)(ws + 67108864);
  _Float16* WFG = (_Float16*)(ws + 100663296);
  _Float16* WRh = (_Float16*)(ws + 103284736);
  _Float16* WIh = (_Float16*)(ws + 103940096);
  _Float16* W1h = (_Float16*)(ws + 104005632);
  _Float16* W2h = (_Float16*)(ws + 104136704);

  prep_kernel<<<dim3(512), dim3(256), 0, stream>>>(Wi, Wf, Wg, Wr, W1, W2,
                                                   WIh, WFG, WRh, W1h, W2h);
  input_kernel<<<dim3(TT / 64, 8), dim3(256), 0, stream>>>(inputs, WIh, bi, R0);

  int S = 0;
  for (int l = 0; l < NL; ++l) {
    int d = 1 << (l % 10);
    int ustart = S + d;
    const float* rin = (l == 0) ? R0 : ((l & 1) ? P : Q);
    float* rout = (l & 1) ? Q : P;
    int Lout = TT - ustart;
    int nblk = (Lout + 63) / 64;
    layer_kernel<<<dim3(nblk, 8), dim3(256), 0, stream>>>(
        rin, rout, WFG + (size_t)l * 65536, WRh + (size_t)l * 16384,
        bf + l * 128, bg + l * 128, br + l * 128, d, ustart);
    S = ustart;
  }
  // after l=19 (odd), final res is in Q
  head_kernel<<<dim3((TGT + 31) / 32, 8), dim3(256), 0, stream>>>(Q, R0, W1h, W2h, b1, b2, out);
}

// Round 2
// 857.466 us; speedup vs baseline: 1.2510x; 1.2510x over previous
//
#include <hip/hip_runtime.h>

// WaveNet on gfx950, fp16 MFMA path, round 2.
// Changes vs r1: fp16 res master (half the activation traffic, copy-only staging),
// layer kernel N=128/block 512thr with K-split staging (2 blocks/CU), head kernel
// N=64/block with mid-dim split (2x256), fp16 out transpose.

#define TT 8192
#define HIDC 128
#define GOODC 2046
#define TGT 6146
#define NL 20

typedef _Float16 half8_t __attribute__((ext_vector_type(8)));
typedef _Float16 half4_t __attribute__((ext_vector_type(4)));
typedef float floatx4 __attribute__((ext_vector_type(4)));

__device__ __forceinline__ floatx4 mfma16(half8_t a, half8_t b, floatx4 c) {
  return __builtin_amdgcn_mfma_f32_16x16x32_f16(a, b, c, 0, 0, 0);
}

// ---------------- weight prep: fp32 -> fp16, stacked layouts ----------------
__global__ void prep_kernel(const float* __restrict__ Wi, const float* __restrict__ Wf,
                            const float* __restrict__ Wg, const float* __restrict__ Wr,
                            const float* __restrict__ W1, const float* __restrict__ W2,
                            _Float16* __restrict__ WIh, _Float16* __restrict__ WFG,
                            _Float16* __restrict__ WRh, _Float16* __restrict__ W1h,
                            _Float16* __restrict__ W2h) {
  int idx = blockIdx.x * blockDim.x + threadIdx.x;
  int stride = gridDim.x * blockDim.x;
  // WFG[l][m][k]: m<128 -> Wf row m, else Wg row m-128; k<128 -> tap0 (u-d), else tap1 (u)
  for (int i = idx; i < NL * 256 * 256; i += stride) {
    int l = i >> 16; int m = (i >> 8) & 255; int k = i & 255;
    int tap = k >> 7; int ci = k & 127;
    float v;
    if (m < 128) v = Wf[(((size_t)l * 128 + m) * 128 + ci) * 2 + tap];
    else         v = Wg[(((size_t)l * 128 + (m - 128)) * 128 + ci) * 2 + tap];
    WFG[i] = (_Float16)v;
  }
  for (int i = idx; i < NL * 128 * 128; i += stride) WRh[i] = (_Float16)Wr[i];
  for (int i = idx; i < 128 * 256; i += stride) WIh[i] = (_Float16)Wi[i];
  for (int i = idx; i < 512 * 128; i += stride) W1h[i] = (_Float16)W1[i];
  for (int i = idx; i < 256 * 512; i += stride) W2h[i] = (_Float16)W2[i];
}

// ---------------- input 1x1 conv: R0[b][u][c] = Wi @ inputs + bi (fp16 out) ----------------
__global__ __launch_bounds__(256, 3) void input_kernel(
    const float* __restrict__ inp, const _Float16* __restrict__ WIh,
    const float* __restrict__ bi, _Float16* __restrict__ R0) {
  __shared__ __align__(16) _Float16 Xs[64][264];  // [n][k=256], pad 8
  const int tid = threadIdx.x;
  const int lane = tid & 63;
  const int w = tid >> 6;
  const int ml = lane & 15;
  const int mq = lane >> 4;
  const int b = blockIdx.y;
  const int u0 = blockIdx.x * 64;
  const float* ib = inp + (size_t)b * 256 * TT;

  for (int i = tid; i < 64 * 16; i += 256) {
    int n4 = i & 15;
    int kg = i >> 4;
    const float* src = ib + (size_t)(kg * 4) * TT + u0 + n4 * 4;
    floatx4 c0 = *(const floatx4*)(src);
    floatx4 c1 = *(const floatx4*)(src + TT);
    floatx4 c2 = *(const floatx4*)(src + 2 * TT);
    floatx4 c3 = *(const floatx4*)(src + 3 * TT);
#pragma unroll
    for (int t = 0; t < 4; ++t) {
      half4_t h;
      h[0] = (_Float16)c0[t]; h[1] = (_Float16)c1[t];
      h[2] = (_Float16)c2[t]; h[3] = (_Float16)c3[t];
      *(half4_t*)&Xs[n4 * 4 + t][kg * 4] = h;
    }
  }
  __syncthreads();

  floatx4 acc[2][4];
#pragma unroll
  for (int a = 0; a < 2; ++a)
#pragma unroll
    for (int c = 0; c < 4; ++c) acc[a][c] = floatx4{0.f, 0.f, 0.f, 0.f};

  const _Float16* Aw = WIh + (size_t)(32 * w + ml) * 256;
  for (int kk = 0; kk < 8; ++kk) {
    const int ko = kk * 32 + mq * 8;
    half8_t a0 = *(const half8_t*)(Aw + ko);
    half8_t a1 = *(const half8_t*)(Aw + 16 * 256 + ko);
#pragma unroll
    for (int nt = 0; nt < 4; ++nt) {
      half8_t bv = *(const half8_t*)&Xs[nt * 16 + ml][ko];
      acc[0][nt] = mfma16(a0, bv, acc[0][nt]);
      acc[1][nt] = mfma16(a1, bv, acc[1][nt]);
    }
  }
  __syncthreads();
  float* Xf = (float*)&Xs[0][0];  // reuse as [64][132] fp32
#pragma unroll
  for (int mt = 0; mt < 2; ++mt) {
    const int mb = 32 * w + mt * 16 + mq * 4;
#pragma unroll
    for (int nt = 0; nt < 4; ++nt)
      *(floatx4*)&Xf[(nt * 16 + ml) * 132 + mb] = acc[mt][nt];
  }
  __syncthreads();
  _Float16* Rb = R0 + (size_t)b * TT * HIDC;
  for (int i = tid; i < 64 * 16; i += 256) {
    int n = i >> 4; int c = i & 15;
    floatx4 x0 = *(const floatx4*)&Xf[n * 132 + c * 8];
    floatx4 x1 = *(const floatx4*)&Xf[n * 132 + c * 8 + 4];
    floatx4 b0 = *(const floatx4*)(bi + c * 8);
    floatx4 b1v = *(const floatx4*)(bi + c * 8 + 4);
    half8_t h;
#pragma unroll
    for (int t = 0; t < 4; ++t) {
      h[t] = (_Float16)(x0[t] + b0[t]);
      h[4 + t] = (_Float16)(x1[t] + b1v[t]);
    }
    *(half8_t*)(Rb + (size_t)(u0 + n) * HIDC + c * 8) = h;
  }
}

// ---------------- one residual layer: N=128/block, K-split staging ----------------
__global__ __launch_bounds__(512, 4) void layer_kernel(
    const _Float16* __restrict__ Rin, _Float16* __restrict__ Rout,
    const _Float16* __restrict__ WFG, const _Float16* __restrict__ WR,
    const float* __restrict__ bf, const float* __restrict__ bg,
    const float* __restrict__ br, int d, int ustart) {
  __shared__ __align__(16) _Float16 Xs[128][136];  // staged tap tile [n][k=128]
  __shared__ __align__(16) _Float16 Os[128][136];  // gated out / x [n][m=128]
  const int tid = threadIdx.x;
  const int lane = tid & 63;
  const int w = tid >> 6;   // 0..7
  const int wm = w & 3;     // m-group (32 f-rows + 32 g-rows)
  const int wn = w >> 2;    // n-half (64 timesteps)
  const int ml = lane & 15;
  const int mq = lane >> 4;
  const int b = blockIdx.y;
  const int u0 = ustart + blockIdx.x * 128;
  const _Float16* Rb = Rin + (size_t)b * TT * HIDC;
  _Float16* Ro = Rout + (size_t)b * TT * HIDC;

  floatx4 accF[2][4], accG[2][4];
#pragma unroll
  for (int a = 0; a < 2; ++a)
#pragma unroll
    for (int c = 0; c < 4; ++c) {
      accF[a][c] = floatx4{0.f, 0.f, 0.f, 0.f};
      accG[a][c] = floatx4{0.f, 0.f, 0.f, 0.f};
    }

  // two K-passes: p=0 tap (u-d) with WFG k[0,128); p=1 tap (u) with k[128,256)
  for (int p = 0; p < 2; ++p) {
    for (int i = tid; i < 128 * 16; i += 512) {
      int n = i >> 4; int c = i & 15;
      int u = u0 + n - (p ? 0 : d);
      if (u > TT - 1) u = TT - 1;  // tail clamp (masked at write)
      *(half8_t*)&Xs[n][c * 8] = *(const half8_t*)(Rb + (size_t)u * HIDC + c * 8);
    }
    __syncthreads();
    const _Float16* Af = WFG + (size_t)(32 * wm + ml) * 256 + p * 128;
    const _Float16* Ag = WFG + (size_t)(128 + 32 * wm + ml) * 256 + p * 128;
    for (int kk = 0; kk < 4; ++kk) {
      const int ko = kk * 32 + mq * 8;
      half8_t aF0 = *(const half8_t*)(Af + ko);
      half8_t aF1 = *(const half8_t*)(Af + 16 * 256 + ko);
      half8_t aG0 = *(const half8_t*)(Ag + ko);
      half8_t aG1 = *(const half8_t*)(Ag + 16 * 256 + ko);
#pragma unroll
      for (int nt = 0; nt < 4; ++nt) {
        half8_t bv = *(const half8_t*)&Xs[wn * 64 + nt * 16 + ml][ko];
        accF[0][nt] = mfma16(aF0, bv, accF[0][nt]);
        accF[1][nt] = mfma16(aF1, bv, accF[1][nt]);
        accG[0][nt] = mfma16(aG0, bv, accG[0][nt]);
        accG[1][nt] = mfma16(aG1, bv, accG[1][nt]);
      }
    }
    __syncthreads();  // p=0: before restage; p=1: uniform
  }
  // NOTE: Xs now holds tap1 = R_old[u0..u0+128) -- reused for the residual add.

  // gate: out = tanh(f+bf) * sigmoid(g+bg) -> Os[n][m]
#pragma unroll
  for (int mt = 0; mt < 2; ++mt) {
    const int mb = 32 * wm + mt * 16 + mq * 4;
    floatx4 bfv = *(const floatx4*)(bf + mb);
    floatx4 bgv = *(const floatx4*)(bg + mb);
#pragma unroll
    for (int nt = 0; nt < 4; ++nt) {
      half4_t o;
#pragma unroll
      for (int r = 0; r < 4; ++r) {
        float fp = accF[mt][nt][r] + bfv[r];
        float gp = accG[mt][nt][r] + bgv[r];
        float fv = 2.0f / (1.0f + __expf(-2.0f * fp)) - 1.0f;
        float gv = 1.0f / (1.0f + __expf(-gp));
        o[r] = (_Float16)(fv * gv);
      }
      *(half4_t*)&Os[wn * 64 + nt * 16 + ml][mb] = o;
    }
  }
  __syncthreads();

  // GEMM2: x = WR(128x128) @ out
  floatx4 accX[2][4];
#pragma unroll
  for (int a = 0; a < 2; ++a)
#pragma unroll
    for (int c = 0; c < 4; ++c) accX[a][c] = floatx4{0.f, 0.f, 0.f, 0.f};
  const _Float16* Ar = WR + (size_t)(32 * wm + ml) * 128;
#pragma unroll
  for (int kk = 0; kk < 4; ++kk) {
    const int ko = kk * 32 + mq * 8;
    half8_t a0 = *(const half8_t*)(Ar + ko);
    half8_t a1 = *(const half8_t*)(Ar + 16 * 128 + ko);
#pragma unroll
    for (int nt = 0; nt < 4; ++nt) {
      half8_t bv = *(const half8_t*)&Os[wn * 64 + nt * 16 + ml][ko];
      accX[0][nt] = mfma16(a0, bv, accX[0][nt]);
      accX[1][nt] = mfma16(a1, bv, accX[1][nt]);
    }
  }
  __syncthreads();  // all Os reads done

  // fp16 transpose of x back into Os
#pragma unroll
  for (int mt = 0; mt < 2; ++mt) {
    const int mb = 32 * wm + mt * 16 + mq * 4;
#pragma unroll
    for (int nt = 0; nt < 4; ++nt) {
      half4_t h;
#pragma unroll
      for (int r = 0; r < 4; ++r) h[r] = (_Float16)accX[mt][nt][r];
      *(half4_t*)&Os[wn * 64 + nt * 16 + ml][mb] = h;
    }
  }
  __syncthreads();

  // epilogue: R_new = x + br + R_old (R_old = Xs from pass 1, in LDS)
  for (int i = tid; i < 128 * 16; i += 512) {
    int n = i >> 4; int c = i & 15;
    int u = u0 + n;
    if (u < TT) {
      half8_t xv = *(const half8_t*)&Os[n][c * 8];
      half8_t rv = *(const half8_t*)&Xs[n][c * 8];
      floatx4 b0 = *(const floatx4*)(br + c * 8);
      floatx4 b1v = *(const floatx4*)(br + c * 8 + 4);
      half8_t o;
#pragma unroll
      for (int t = 0; t < 4; ++t) {
        o[t] = (_Float16)((float)xv[t] + (float)rv[t] + b0[t]);
        o[4 + t] = (_Float16)((float)xv[4 + t] + (float)rv[4 + t] + b1v[t]);
      }
      *(half8_t*)(Ro + (size_t)u * HIDC + c * 8) = o;
    }
  }
}

// ---------------- head: out = W2 @ relu(W1 @ relu(R20-R0) + b1) + b2 ----------------
// N=64/block, 512 threads, mid dim split into 2 passes of 256.
__global__ __launch_bounds__(512, 4) void head_kernel(
    const _Float16* __restrict__ Rfin, const _Float16* __restrict__ R0,
    const _Float16* __restrict__ W1h, const _Float16* __restrict__ W2h,
    const float* __restrict__ b1, const float* __restrict__ b2,
    float* __restrict__ out) {
  __shared__ __align__(16) _Float16 Hs[64][136];   // relu(final) [n][c=128]
  __shared__ __align__(16) _Float16 H1s[64][264];  // mid half [n][m=256]
  const int tid = threadIdx.x;
  const int lane = tid & 63;
  const int w = tid >> 6;  // 0..7
  const int ml = lane & 15;
  const int mq = lane >> 4;
  const int b = blockIdx.y;
  const int u0 = GOODC + blockIdx.x * 64;
  const _Float16* Ra = Rfin + (size_t)b * TT * HIDC;
  const _Float16* Rz = R0 + (size_t)b * TT * HIDC;

  for (int i = tid; i < 64 * 16; i += 512) {
    int n = i >> 4; int c = i & 15;
    int u = u0 + n; if (u > TT - 1) u = TT - 1;
    half8_t a = *(const half8_t*)(Ra + (size_t)u * HIDC + c * 8);
    half8_t z = *(const half8_t*)(Rz + (size_t)u * HIDC + c * 8);
    half8_t h;
#pragma unroll
    for (int t = 0; t < 8; ++t) {
      float v = (float)a[t] - (float)z[t];
      h[t] = (_Float16)(v > 0.f ? v : 0.f);
    }
    *(half8_t*)&Hs[n][c * 8] = h;
  }
  __syncthreads();

  floatx4 acc2[2][4];
#pragma unroll
  for (int a = 0; a < 2; ++a)
#pragma unroll
    for (int c = 0; c < 4; ++c) acc2[a][c] = floatx4{0.f, 0.f, 0.f, 0.f};

  for (int p = 0; p < 2; ++p) {
    // GEMM1: mid rows [256p, 256p+256), wave w owns 32 rows; K=128, N=64
    floatx4 acc1[2][4];
#pragma unroll
    for (int a = 0; a < 2; ++a)
#pragma unroll
      for (int c = 0; c < 4; ++c) acc1[a][c] = floatx4{0.f, 0.f, 0.f, 0.f};
    const _Float16* A1 = W1h + (size_t)(256 * p + 32 * w + ml) * 128;
#pragma unroll
    for (int kk = 0; kk < 4; ++kk) {
      const int ko = kk * 32 + mq * 8;
      half8_t av0 = *(const half8_t*)(A1 + ko);
      half8_t av1 = *(const half8_t*)(A1 + 16 * 128 + ko);
#pragma unroll
      for (int nt = 0; nt < 4; ++nt) {
        half8_t bv = *(const half8_t*)&Hs[nt * 16 + ml][ko];
        acc1[0][nt] = mfma16(av0, bv, acc1[0][nt]);
        acc1[1][nt] = mfma16(av1, bv, acc1[1][nt]);
      }
    }
    __syncthreads();  // previous pass's H1s reads complete
#pragma unroll
    for (int mt = 0; mt < 2; ++mt) {
      const int mb = 32 * w + mt * 16 + mq * 4;
      floatx4 bv = *(const floatx4*)(b1 + 256 * p + mb);
#pragma unroll
      for (int nt = 0; nt < 4; ++nt) {
        half4_t h;
#pragma unroll
        for (int r = 0; r < 4; ++r) {
          float v = acc1[mt][nt][r] + bv[r];
          h[r] = (_Float16)(v > 0.f ? v : 0.f);
        }
        *(half4_t*)&H1s[nt * 16 + ml][mb] = h;
      }
    }
    __syncthreads();
    // GEMM2 accumulate: out rows 32w..32w+32, K=256 (this mid half)
    const _Float16* A2 = W2h + (size_t)(32 * w + ml) * 512 + p * 256;
    for (int kk = 0; kk < 8; ++kk) {
      const int ko = kk * 32 + mq * 8;
      half8_t av0 = *(const half8_t*)(A2 + ko);
      half8_t av1 = *(const half8_t*)(A2 + 16 * 512 + ko);
#pragma unroll
      for (int nt = 0; nt < 4; ++nt) {
        half8_t bv = *(const half8_t*)&H1s[nt * 16 + ml][ko];
        acc2[0][nt] = mfma16(av0, bv, acc2[0][nt]);
        acc2[1][nt] = mfma16(av1, bv, acc2[1][nt]);
      }
    }
    __syncthreads();  // H1s reads done before next pass overwrites
  }

  // fp16 out transpose into H1s (reused as [64][264] halfs, cols = 256 out ch)
#pragma unroll
  for (int mt = 0; mt < 2; ++mt) {
    const int mb = 32 * w + mt * 16 + mq * 4;
    floatx4 bv = *(const floatx4*)(b2 + mb);
#pragma unroll
    for (int nt = 0; nt < 4; ++nt) {
      half4_t h;
#pragma unroll
      for (int r = 0; r < 4; ++r) h[r] = (_Float16)(acc2[mt][nt][r] + bv[r]);
      *(half4_t*)&H1s[nt * 16 + ml][mb] = h;
    }
  }
  __syncthreads();
  for (int i = tid; i < 64 * 32; i += 512) {
    int n = i >> 5; int g = i & 31;
    int u = u0 + n;
    if (u < TT) {
      half8_t v = *(const half8_t*)&H1s[n][g * 8];
      float* dst = out + ((size_t)b * TGT + (u - GOODC)) * 256 + g * 8;
      floatx4 v0, v1;
#pragma unroll
      for (int t = 0; t < 4; ++t) { v0[t] = (float)v[t]; v1[t] = (float)v[4 + t]; }
      *(floatx4*)dst = v0;
      *(floatx4*)(dst + 4) = v1;
    }
  }
}

extern "C" void kernel_launch(void* const* d_in, const int* in_sizes, int n_in,
                              void* d_out, int out_size, void* d_ws, size_t ws_size,
                              hipStream_t stream) {
  const float* inputs = (const float*)d_in[0];
  const float* Wi = (const float*)d_in[1];
  const float* bi = (const float*)d_in[2];
  const float* Wf = (const float*)d_in[3];
  const float* bf = (const float*)d_in[4];
  const float* Wg = (const float*)d_in[5];
  const float* bg = (const float*)d_in[6];
  const float* Wr = (const float*)d_in[7];
  const float* br = (const float*)d_in[8];
  const float* W1 = (const float*)d_in[9];
  const float* b1 = (const float*)d_in[10];
  const float* W2 = (const float*)d_in[11];
  const float* b2 = (const float*)d_in[12];
  float* out = (float*)d_out;

  // workspace layout (~54 MB): three fp16 res buffers + fp16 weights
  char* ws = (char*)d_ws;
  _Float16* R0h = (_Float16*)(ws + 0);          // 16,777,216 B
  _Float16* Ph  = (_Float16*)(ws + 16777216);
  _Float16* Qh  = (_Float16*)(ws + 33554432);
  _Float16* WFG = (_Float16*)(ws + 50331648);   // 2,621,440 B
  _Float16* WRh = (_Float16*)(ws + 52953088);   // 655,360 B
  _Float16* WIh = (_Float16*)(ws + 53608448);   // 65,536 B
  _Float16* W1h = (_Float16*)(ws + 53673984);   // 131,072 B
  _Float16* W2h = (_Float16*)(ws + 53805056);   // 262,144 B

  prep_kernel<<<dim3(512), dim3(256), 0, stream>>>(Wi, Wf, Wg, Wr, W1, W2,
                                                   WIh, WFG, WRh, W1h, W2h);
  input_kernel<<<dim3(TT / 64, 8), dim3(256), 0, stream>>>(inputs, WIh, bi, R0h);

  int S = 0;
  for (int l = 0; l < NL; ++l) {
    int d = 1 << (l % 10);
    int ustart = S + d;
    const _Float16* rin = (l == 0) ? R0h : ((l & 1) ? Ph : Qh);
    _Float16* rout = (l & 1) ? Qh : Ph;
    int Lout = TT - ustart;
    int nblk = (Lout + 127) / 128;
    layer_kernel<<<dim3(nblk, 8), dim3(512), 0, stream>>>(
        rin, rout, WFG + (size_t)l * 65536, WRh + (size_t)l * 16384,
        bf + l * 128, bg + l * 128, br + l * 128, d, ustart);
    S = ustart;
  }
  // after l=19 (odd), final res is in Qh
  head_kernel<<<dim3((TGT + 63) / 64, 8), dim3(512), 0, stream>>>(
      Qh, R0h, W1h, W2h, b1, b2, out);
}